// Round 16
// baseline (37.738 us; speedup 1.0000x reference)
//
#include <hip/hip_runtime.h>
#include <hip/hip_bf16.h>

// Problem constants: B=32768, D=768, C=200.
#define NROWS 32768
#define DIMS  768
#define NC    200
#define CPAD  256
#define KSTEP 32
#define NSTEP (DIMS / KSTEP)   // 24
#define ROWSB 128              // M-tile rows per block -> grid 256 (1 block/CU)

typedef __attribute__((ext_vector_type(8))) short short8;   // 8 bf16
typedef __attribute__((ext_vector_type(4))) float f32x4;

#define WAITV4 asm volatile("s_waitcnt vmcnt(4)" ::: "memory")
#define WAITL0 asm volatile("s_waitcnt lgkmcnt(0)" ::: "memory")
#define BAR    __builtin_amdgcn_s_barrier()

__device__ __forceinline__ unsigned pk_bf16(float lo, float hi) {
  union { __hip_bfloat162 h; unsigned u; } c;
  c.h = __float22bfloat162_rn(make_float2(lo, hi));
  return c.u;
}

// Kernel 1 (unchanged): L2-normalize centers -> bf16, K-blocked by 32:
// (c,d) -> cnb2[(d>>5)*CPAD*KSTEP + c*KSTEP + (d&31)]; rows >= NC zero. Zeroes out.
__global__ __launch_bounds__(256) void prep_centers_k(const float* __restrict__ centers,
                                                      short* __restrict__ cnb2,
                                                      float* __restrict__ out) {
  const int c = blockIdx.x;
  const int tid = threadIdx.x;
  if (c == 0 && tid == 0) out[0] = 0.f;
  if (c >= NC) {
    for (int d = tid; d < DIMS; d += 256)
      cnb2[(d >> 5) * (CPAD * KSTEP) + c * KSTEP + (d & 31)] = 0;
    return;
  }
  float ssq = 0.f;
  for (int d = tid; d < DIMS; d += 256) {
    float v = centers[c * DIMS + d];
    ssq += v * v;
  }
#pragma unroll
  for (int off = 32; off > 0; off >>= 1) ssq += __shfl_down(ssq, off);
  __shared__ float red[4];
  const int wid = tid >> 6, lane = tid & 63;
  if (lane == 0) red[wid] = ssq;
  __syncthreads();
  const float tot = red[0] + red[1] + red[2] + red[3];
  const float inv = 1.f / fmaxf(sqrtf(tot), 1e-8f);
  for (int d = tid; d < DIMS; d += 256) {
    const float v = centers[c * DIMS + d] * inv;
    union { __hip_bfloat16 h; short s; } cv;
    cv.h = __float2bfloat16(v);
    cnb2[(d >> 5) * (CPAD * KSTEP) + c * KSTEP + (d & 31)] = cv.s;
  }
}

// Kernel 2: producer-consumer, ROWSB=128 (HALVED B-from-L2 traffic).
//  - Consumers (waves 0-3): 128x64 tile, acc[8][4] (128 VGPR); staggered B reload.
//  - Producers (waves 4-7): 2 thr/row, 4xfloat4 depth-2 slots, cvt, 2 ds_writes.
//  - rdq swizzle row-invariant across mi ((mi*16) ≡ 0 mod 4 in (row>>1)&3).
// Barrier contract: 1 prologue + 24 phases + 1 invs + __syncthreads.
// MFMA frag mapping (verified rounds 2-15): A lane=A[m][kg*8+j];
// B lane=B[kg*8+j][m]; D: col=m, row=kg*4+reg.
__global__ __launch_bounds__(512, 2) void cos_loss_k(
    const float* __restrict__ feats,
    const short* __restrict__ cnb2,
    const int* __restrict__ labels,
    const int* __restrict__ labelled,
    float* __restrict__ out) {
  const int tid = threadIdx.x;
  const int wid = tid >> 6;          // 0-3 consumers, 4-7 producers
  const int lane = tid & 63;
  const int rowBase = blockIdx.x * ROWSB;

  __shared__ short As[2][ROWSB][32];   // 16 KB, dbuf
  __shared__ float invs[ROWSB];
  __shared__ float l1part[4][ROWSB];
  __shared__ float alpart[4][ROWSB];

  if (wid < 4) {
    // =========================== CONSUMER ===========================
    const int m = lane & 15;
    const int kg = lane >> 4;
    const int rdq = (kg ^ ((m >> 1) & 3)) * 8;   // swizzled A-frag quad offset
    const short* bp = cnb2 + (size_t)(wid * 64 + m) * KSTEP + kg * 8;

    f32x4 acc[8][4];
#pragma unroll
    for (int mi = 0; mi < 8; ++mi)
#pragma unroll
      for (int ni = 0; ni < 4; ++ni) acc[mi][ni] = (f32x4){0.f, 0.f, 0.f, 0.f};

    short8 B[4];   // single staggered slot (16 VGPR)

#define BLOAD(ni, s) \
    B[ni] = *(const short8*)(bp + (size_t)(s) * (CPAD * KSTEP) + (ni) * (16 * KSTEP))

    // prologue: B for step 0; A buf0 published at the barrier
    BLOAD(0, 0); BLOAD(1, 0); BLOAD(2, 0); BLOAD(3, 0);
    BAR;   // barrier 0

#define PHASEC(p, ab) do {                                               \
    const int sn_ = ((p) + 1 < NSTEP) ? (p) + 1 : NSTEP - 1;             \
    short8 af[8];                                                        \
    _Pragma("unroll")                                                    \
    for (int mi = 0; mi < 8; ++mi)                                       \
      af[mi] = *(const short8*)(&As[(ab)][mi * 16 + m][rdq]);            \
    __builtin_amdgcn_s_setprio(1);                                       \
    _Pragma("unroll")                                                    \
    for (int ni = 0; ni < 4; ++ni) {                                     \
      _Pragma("unroll")                                                  \
      for (int mi = 0; mi < 8; ++mi)                                     \
        acc[mi][ni] = __builtin_amdgcn_mfma_f32_16x16x32_bf16(           \
            af[mi], B[ni], acc[mi][ni], 0, 0, 0);                        \
      BLOAD(ni, sn_);                                                    \
    }                                                                    \
    __builtin_amdgcn_s_setprio(0);                                       \
    BAR;                                                                 \
  } while (0)

    for (int p = 0; p < NSTEP; p += 2) {
      PHASEC(p, 0);
      PHASEC(p + 1, 1);
    }
#undef BLOAD
#undef PHASEC

    BAR;   // barrier 26: invs published by producers

    // epilogue: per-row l1 and label-|cos|
#pragma unroll
    for (int mi = 0; mi < 8; ++mi) {
      float l1r[4] = {0.f, 0.f, 0.f, 0.f};
      float alr[4] = {0.f, 0.f, 0.f, 0.f};
      float iv[4];
      int labr[4];
#pragma unroll
      for (int r = 0; r < 4; ++r) {
        const int row = mi * 16 + kg * 4 + r;
        iv[r] = invs[row];
        labr[r] = labels[rowBase + row];
      }
#pragma unroll
      for (int ni = 0; ni < 4; ++ni) {
        const int col = wid * 64 + ni * 16 + m;
#pragma unroll
        for (int r = 0; r < 4; ++r) {
          const float a = fabsf(acc[mi][ni][r] * iv[r]);
          l1r[r] += a;
          if (col == labr[r]) alr[r] += a;
        }
      }
#pragma unroll
      for (int r = 0; r < 4; ++r) {
#pragma unroll
        for (int off = 1; off < 16; off <<= 1) {
          l1r[r] += __shfl_xor(l1r[r], off);
          alr[r] += __shfl_xor(alr[r], off);
        }
      }
      if (m == 0) {
#pragma unroll
        for (int r = 0; r < 4; ++r) {
          l1part[wid][mi * 16 + kg * 4 + r] = l1r[r];
          alpart[wid][mi * 16 + kg * 4 + r] = alr[r];
        }
      }
    }
  } else {
    // =========================== PRODUCER ===========================
    const int pt = (wid - 4) * 64 + lane;    // 0..255
    const int arow = pt >> 1;                // 2 thr/row (0..127)
    const int ah   = pt & 1;                 // half: 16 floats
    const int rs   = (arow >> 1) & 3;        // row quad swizzle
    const int lq   = ah * 2;                 // logical quads lq, lq+1
    const float* asrc = feats + (size_t)(rowBase + arow) * DIMS + ah * 16;
    const int pq0 = (lq ^ rs) * 8;           // phys short offsets
    const int pq1 = ((lq + 1) ^ rs) * 8;

    float ssq = 0.f;
    float4 S0a, S0b, S0c, S0d, S1a, S1b, S1c, S1d;   // depth-2 slots

#define LOADA(P, s) do {                                                 \
    const float* ap_ = asrc + (s) * KSTEP;                               \
    P##a = *(const float4*)(ap_);                                        \
    P##b = *(const float4*)(ap_ + 4);                                    \
    P##c = *(const float4*)(ap_ + 8);                                    \
    P##d = *(const float4*)(ap_ + 12);                                   \
  } while (0)

#define WRITEA(P, buf, guard) do {                                       \
    if (guard) {                                                         \
      ssq += P##a.x*P##a.x + P##a.y*P##a.y + P##a.z*P##a.z + P##a.w*P##a.w; \
      ssq += P##b.x*P##b.x + P##b.y*P##b.y + P##b.z*P##b.z + P##b.w*P##b.w; \
      ssq += P##c.x*P##c.x + P##c.y*P##c.y + P##c.z*P##c.z + P##c.w*P##c.w; \
      ssq += P##d.x*P##d.x + P##d.y*P##d.y + P##d.z*P##d.z + P##d.w*P##d.w; \
    }                                                                    \
    union { short8 s8; unsigned u[4]; } q0_, q1_;                        \
    q0_.u[0] = pk_bf16(P##a.x, P##a.y); q0_.u[1] = pk_bf16(P##a.z, P##a.w); \
    q0_.u[2] = pk_bf16(P##b.x, P##b.y); q0_.u[3] = pk_bf16(P##b.z, P##b.w); \
    q1_.u[0] = pk_bf16(P##c.x, P##c.y); q1_.u[1] = pk_bf16(P##c.z, P##c.w); \
    q1_.u[2] = pk_bf16(P##d.x, P##d.y); q1_.u[3] = pk_bf16(P##d.z, P##d.w); \
    *(short8*)(&As[(buf)][arow][pq0]) = q0_.s8;                          \
    *(short8*)(&As[(buf)][arow][pq1]) = q1_.s8;                          \
  } while (0)

#define CLMP(x) (((x) < NSTEP) ? (x) : NSTEP - 1)

    // prologue: load steps 0,1; publish step 0 -> buf0
    LOADA(S0, 0);
    LOADA(S1, 1);
    WAITV4;            // S0 ready; S1 in flight
    WRITEA(S0, 0, true);
    WAITL0;
    BAR;   // barrier 0

    for (int p = 0; p < NSTEP; p += 2) {
      // phase p: prefetch p+2 into S0; publish step p+1 (S1) -> buf1
      LOADA(S0, CLMP(p + 2));
      WAITV4;          // S1 (step p+1) ready; S0 in flight
      WRITEA(S1, 1, (p + 1 < NSTEP));
      WAITL0;
      BAR;
      // phase p+1: prefetch p+3 into S1; publish step p+2 (S0) -> buf0
      LOADA(S1, CLMP(p + 3));
      WAITV4;          // S0 (step p+2) ready
      WRITEA(S0, 0, (p + 2 < NSTEP));
      WAITL0;
      BAR;
    }
#undef LOADA
#undef WRITEA
#undef CLMP

    // row inverse norms: reduce over the 2 staging lanes of each row
    ssq += __shfl_xor(ssq, 1);
    if ((lane & 1) == 0) invs[arow] = 1.f / fmaxf(sqrtf(ssq), 1e-8f);
    WAITL0;
    BAR;   // barrier 26: invs published
  }

  __syncthreads();     // l1part/alpart published + full drain

  if (tid < ROWSB) {
    const float L = l1part[0][tid] + l1part[1][tid] + l1part[2][tid] + l1part[3][tid];
    const float A = alpart[0][tid] + alpart[1][tid] + alpart[2][tid] + alpart[3][tid];
    float c = labelled[rowBase + tid] ? (L - 2.f * A) / fmaxf(L, 1e-12f) : 0.f;
#pragma unroll
    for (int off = 1; off < 64; off <<= 1) c += __shfl_xor(c, off);
    if ((tid & 63) == 0) atomicAdd(out, c);
  }
}

extern "C" void kernel_launch(void* const* d_in, const int* in_sizes, int n_in,
                              void* d_out, int out_size, void* d_ws, size_t ws_size,
                              hipStream_t stream) {
  const float* feats = (const float*)d_in[0];
  const float* centers = (const float*)d_in[1];
  const int* labels = (const int*)d_in[2];
  const int* labelled = (const int*)d_in[3];
  float* out = (float*)d_out;
  short* cnb2 = (short*)d_ws;  // [24][256][32] bf16 = 393216 B

  prep_centers_k<<<CPAD, 256, 0, stream>>>(centers, cnb2, out);
  cos_loss_k<<<NROWS / ROWSB, 512, 0, stream>>>(feats, cnb2, labels, labelled, out);
}

// Round 17
// 35.568 us; speedup vs baseline: 1.0610x; 1.0610x over previous
//
#include <hip/hip_runtime.h>
#include <hip/hip_bf16.h>

// Problem constants: B=32768, D=768, C=200.
#define NROWS 32768
#define DIMS  768
#define NC    200
#define CPAD  256
#define KSTEP 32
#define NSTEP (DIMS / KSTEP)   // 24
#define ROWSB 64               // M-tile rows per block -> grid 512

typedef __attribute__((ext_vector_type(8))) short short8;   // 8 bf16
typedef __attribute__((ext_vector_type(4))) float f32x4;

#define WAITV2 asm volatile("s_waitcnt vmcnt(2)" ::: "memory")
#define WAITL0 asm volatile("s_waitcnt lgkmcnt(0)" ::: "memory")
#define BAR    __builtin_amdgcn_s_barrier()

__device__ __forceinline__ unsigned pk_bf16(float lo, float hi) {
  union { __hip_bfloat162 h; unsigned u; } c;
  c.h = __float22bfloat162_rn(make_float2(lo, hi));
  return c.u;
}

// Kernel 1: L2-normalize centers -> bf16, K-blocked by 32:
// (c,d) -> cnb2[(d>>5)*CPAD*KSTEP + c*KSTEP + (d&31)]; rows >= NC zero. Zeroes out.
// (Center norms do NOT cancel in the final ratio; feature norms DO — see kernel 2.)
__global__ __launch_bounds__(256) void prep_centers_k(const float* __restrict__ centers,
                                                      short* __restrict__ cnb2,
                                                      float* __restrict__ out) {
  const int c = blockIdx.x;
  const int tid = threadIdx.x;
  if (c == 0 && tid == 0) out[0] = 0.f;
  if (c >= NC) {
    for (int d = tid; d < DIMS; d += 256)
      cnb2[(d >> 5) * (CPAD * KSTEP) + c * KSTEP + (d & 31)] = 0;
    return;
  }
  float ssq = 0.f;
  for (int d = tid; d < DIMS; d += 256) {
    float v = centers[c * DIMS + d];
    ssq += v * v;
  }
#pragma unroll
  for (int off = 32; off > 0; off >>= 1) ssq += __shfl_down(ssq, off);
  __shared__ float red[4];
  const int wid = tid >> 6, lane = tid & 63;
  if (lane == 0) red[wid] = ssq;
  __syncthreads();
  const float tot = red[0] + red[1] + red[2] + red[3];
  const float inv = 1.f / fmaxf(sqrtf(tot), 1e-8f);
  for (int d = tid; d < DIMS; d += 256) {
    const float v = centers[c * DIMS + d] * inv;
    union { __hip_bfloat16 h; short s; } cv;
    cv.h = __float2bfloat16(v);
    cnb2[(d >> 5) * (CPAD * KSTEP) + c * KSTEP + (d & 31)] = cv.s;
  }
}

// Kernel 2: producer-consumer (round-13 skeleton), feature-norm-free.
// KEY ALGEBRA: per row, contribution = (L - 2A)/max(L, eps) with L,A both
// proportional to inv_f (the feature norm) -> inv_f CANCELS. eps=1e-12 is
// ~20 orders below L (O(10) raw |dot| sums), so the clamp change is invisible
// in fp32. Producers therefore do NO ssq; no invs array; no extra barrier.
//  - Consumers (waves 0-3): 64x64 tile, acc[4][4]; A-frags from LDS dbuf
//    (quad-swizzled); B staggered single-slot reload direct from L2 cnb2;
//    s_setprio(1) around the MFMA cluster.
//  - Producers (waves 4-7): pure load -> cvt_pk -> ds_write, depth-2 slots,
//    uniform unguarded phases (tail-clamped rewrites are idempotent).
// Barrier contract (both paths): 1 prologue + 24 phase BARs + __syncthreads.
// MFMA frag mapping (verified rounds 2-16): A lane=A[m][kg*8+j];
// B lane=B[kg*8+j][m]; D: col=m, row=kg*4+reg.
__global__ __launch_bounds__(512, 4) void cos_loss_k(
    const float* __restrict__ feats,
    const short* __restrict__ cnb2,
    const int* __restrict__ labels,
    const int* __restrict__ labelled,
    float* __restrict__ out) {
  const int tid = threadIdx.x;
  const int wid = tid >> 6;          // 0-3 consumers, 4-7 producers
  const int lane = tid & 63;
  const int rowBase = blockIdx.x * ROWSB;

  __shared__ short As[2][ROWSB][32];   // 8 KB, dbuf
  __shared__ float l1part[4][ROWSB];
  __shared__ float alpart[4][ROWSB];

  if (wid < 4) {
    // =========================== CONSUMER ===========================
    const int m = lane & 15;
    const int kg = lane >> 4;
    const int rdq = (kg ^ ((m >> 1) & 3)) * 8;   // swizzled A-frag quad offset
    const short* bp = cnb2 + (size_t)(wid * 64 + m) * KSTEP + kg * 8;

    f32x4 acc[4][4];
#pragma unroll
    for (int mi = 0; mi < 4; ++mi)
#pragma unroll
      for (int ni = 0; ni < 4; ++ni) acc[mi][ni] = (f32x4){0.f, 0.f, 0.f, 0.f};

    short8 B[4];   // single staggered slot (16 VGPR)

#define BLOAD(ni, s) \
    B[ni] = *(const short8*)(bp + (size_t)(s) * (CPAD * KSTEP) + (ni) * (16 * KSTEP))

    // prologue: B for step 0; A buf0 published at the barrier
    BLOAD(0, 0); BLOAD(1, 0); BLOAD(2, 0); BLOAD(3, 0);
    BAR;   // barrier 0

#define PHASEC(p, ab) do {                                               \
    const int sn_ = ((p) + 1 < NSTEP) ? (p) + 1 : NSTEP - 1;             \
    short8 af[4];                                                        \
    _Pragma("unroll")                                                    \
    for (int mi = 0; mi < 4; ++mi)                                       \
      af[mi] = *(const short8*)(&As[(ab)][mi * 16 + m][rdq]);            \
    __builtin_amdgcn_s_setprio(1);                                       \
    _Pragma("unroll")                                                    \
    for (int ni = 0; ni < 4; ++ni) {                                     \
      _Pragma("unroll")                                                  \
      for (int mi = 0; mi < 4; ++mi)                                     \
        acc[mi][ni] = __builtin_amdgcn_mfma_f32_16x16x32_bf16(           \
            af[mi], B[ni], acc[mi][ni], 0, 0, 0);                        \
      BLOAD(ni, sn_);                                                    \
    }                                                                    \
    __builtin_amdgcn_s_setprio(0);                                       \
    BAR;                                                                 \
  } while (0)

    for (int p = 0; p < NSTEP; p += 2) {
      PHASEC(p, 0);
      PHASEC(p + 1, 1);
    }
#undef BLOAD
#undef PHASEC

    // epilogue: per-row L1 and label-|dot| (feature norm cancelled)
#pragma unroll
    for (int mi = 0; mi < 4; ++mi) {
      float l1r[4] = {0.f, 0.f, 0.f, 0.f};
      float alr[4] = {0.f, 0.f, 0.f, 0.f};
      int labr[4];
#pragma unroll
      for (int r = 0; r < 4; ++r)
        labr[r] = labels[rowBase + mi * 16 + kg * 4 + r];
#pragma unroll
      for (int ni = 0; ni < 4; ++ni) {
        const int col = wid * 64 + ni * 16 + m;
#pragma unroll
        for (int r = 0; r < 4; ++r) {
          const float a = fabsf(acc[mi][ni][r]);
          l1r[r] += a;
          if (col == labr[r]) alr[r] += a;
        }
      }
#pragma unroll
      for (int r = 0; r < 4; ++r) {
#pragma unroll
        for (int off = 1; off < 16; off <<= 1) {
          l1r[r] += __shfl_xor(l1r[r], off);
          alr[r] += __shfl_xor(alr[r], off);
        }
      }
      if (m == 0) {
#pragma unroll
        for (int r = 0; r < 4; ++r) {
          l1part[wid][mi * 16 + kg * 4 + r] = l1r[r];
          alpart[wid][mi * 16 + kg * 4 + r] = alr[r];
        }
      }
    }
  } else {
    // =========================== PRODUCER ===========================
    const int pt = (wid - 4) * 64 + lane;    // 0..255
    const int arow = pt >> 2;                // 4 thr/row
    const int aq   = pt & 3;
    const int aswz = (arow >> 1) & 3;
    const float* asrc = feats + (size_t)(rowBase + arow) * DIMS + aq * 8;
    short* adst0 = &As[0][arow][(aq ^ aswz) * 8];
    short* adst1 = &As[1][arow][(aq ^ aswz) * 8];

    float4 S0lo, S0hi, S1lo, S1hi;   // depth-2 slots

#define LOADA(P, s) do {                                                 \
    const float* ap_ = asrc + (s) * KSTEP;                               \
    P##lo = *(const float4*)(ap_);                                       \
    P##hi = *(const float4*)(ap_ + 4);                                   \
  } while (0)

#define WRITEA(P, dst) do {                                              \
    union { short8 s8; unsigned u[4]; } p_;                              \
    p_.u[0] = pk_bf16(P##lo.x, P##lo.y);                                 \
    p_.u[1] = pk_bf16(P##lo.z, P##lo.w);                                 \
    p_.u[2] = pk_bf16(P##hi.x, P##hi.y);                                 \
    p_.u[3] = pk_bf16(P##hi.z, P##hi.w);                                 \
    *(short8*)(dst) = p_.s8;                                             \
  } while (0)

#define CLMP(x) (((x) < NSTEP) ? (x) : NSTEP - 1)

    // prologue: load steps 0,1; publish step 0 -> buf0
    LOADA(S0, 0);
    LOADA(S1, 1);
    WAITV2;            // S0 ready; S1 in flight
    WRITEA(S0, adst0);
    WAITL0;
    BAR;   // barrier 0

    for (int p = 0; p < NSTEP; p += 2) {
      // phase p: prefetch p+2 into S0; publish step p+1 (S1) -> buf1
      LOADA(S0, CLMP(p + 2));
      WAITV2;          // S1 (step p+1) ready; S0 in flight
      WRITEA(S1, adst1);
      WAITL0;
      BAR;
      // phase p+1: prefetch p+3 into S1; publish step p+2 (S0) -> buf0
      LOADA(S1, CLMP(p + 3));
      WAITV2;          // S0 (step p+2) ready
      WRITEA(S0, adst0);
      WAITL0;
      BAR;
    }
#undef LOADA
#undef WRITEA
#undef CLMP
  }

  __syncthreads();     // l1part/alpart published + full drain

  if (tid < ROWSB) {
    const float L = l1part[0][tid] + l1part[1][tid] + l1part[2][tid] + l1part[3][tid];
    const float A = alpart[0][tid] + alpart[1][tid] + alpart[2][tid] + alpart[3][tid];
    float c = labelled[rowBase + tid] ? (L - 2.f * A) / fmaxf(L, 1e-12f) : 0.f;
#pragma unroll
    for (int off = 1; off < 64; off <<= 1) c += __shfl_xor(c, off);
    if (tid == 0) atomicAdd(out, c);
  }
}

extern "C" void kernel_launch(void* const* d_in, const int* in_sizes, int n_in,
                              void* d_out, int out_size, void* d_ws, size_t ws_size,
                              hipStream_t stream) {
  const float* feats = (const float*)d_in[0];
  const float* centers = (const float*)d_in[1];
  const int* labels = (const int*)d_in[2];
  const int* labelled = (const int*)d_in[3];
  float* out = (float*)d_out;
  short* cnb2 = (short*)d_ws;  // [24][256][32] bf16 = 393216 B

  prep_centers_k<<<CPAD, 256, 0, stream>>>(centers, cnb2, out);
  cos_loss_k<<<NROWS / ROWSB, 512, 0, stream>>>(feats, cnb2, labels, labelled, out);
}